// Round 8
// baseline (6283.577 us; speedup 1.0000x reference)
//
#include <hip/hip_runtime.h>
#include <cstdint>
#include <cstddef>

#define B_ 8
#define C_ 64
#define N_ 4096
#define O_ 64
#define ROWS_ (B_*N_)          // 32768
#define SPLIT_ 4               // m-splits in k_select
#define BUFSTRIDE_ 17          // u64 stride for candidate buffers (r2-proven)

#define TM_ 64                 // n-rows per k_dist block
#define TN_ 128                // m-cols per k_dist block

#define SEL_STR 261            // u32 stride per m-slice in k_select stage (2-way banks)

typedef unsigned long long u64;
typedef unsigned int u32;
typedef unsigned short u16;

// ---- workspace layout (bytes) ----
// xf   [ROWS][64] f32 : 0         (8 MB)
// sq   [ROWS]     f32 : 8388608   (128 KB)
// kd   [ROWS][64] u32 : 8519680   (8 MB)
// ki   [ROWS][64] u16 : 16908288  (4 MB)
// knn  [ROWS][16] i32 : 21102592  (2 MB)
// h    [ROWS][64] f32 : 8519680   (aliases kd, dead after merge)
// h1   [ROWS][64] f32 : 16908288  (aliases ki+knn, dead after aggr)
// bn   sums/params    : 25296896  (1 KB)
// D    [rows_panel][4096] u32 : 25297920 (536 MB / P, panel-sized to ws_size)
#define OFF_XF   0
#define OFF_SQ   8388608
#define OFF_KD   8519680
#define OFF_KI   16908288
#define OFF_IDX  21102592
#define OFF_H    8519680
#define OFF_H1   16908288
#define OFF_BN   25296896
#define OFF_D    25297920

__device__ __forceinline__ void insert16(u64 kv[16], u64 key) {
  if (key < kv[15]) {
#pragma unroll
    for (int j = 15; j > 0; --j) {
      u64 a = kv[j-1], b = kv[j];
      kv[j] = (key < a) ? a : ((key < b) ? key : b);
    }
    kv[0] = (key < kv[0]) ? key : kv[0];
  }
}

// ---------------- K1: transpose [B,C,N] -> xf[B,N,C], plus sq; zero bn ----------------
__global__ __launch_bounds__(256) void k_transpose(const float* __restrict__ x,
                                                   float* __restrict__ xf,
                                                   float* __restrict__ sq,
                                                   float* __restrict__ bn_acc) {
  __shared__ float lds[64 * 65];
  const int b  = blockIdx.x >> 6;          // 8 batches
  const int n0 = (blockIdx.x & 63) << 6;   // 64 n-tiles of 64
  const int tid = threadIdx.x;
  if (blockIdx.x == 0 && tid < 128) bn_acc[tid] = 0.f;
  const float* xb = x + (size_t)b * C_ * N_;
  {
    const int nn = tid & 63;
    const int c0 = tid >> 6;
#pragma unroll
    for (int i = 0; i < 16; ++i) {
      int c = c0 + i * 4;
      lds[c * 65 + nn] = xb[(size_t)c * N_ + n0 + nn];   // coalesced over n
    }
  }
  __syncthreads();
  {
    const int cc  = tid & 63;
    const int nn0 = tid >> 6;
#pragma unroll
    for (int i = 0; i < 16; ++i) {
      int nn = nn0 + i * 4;
      xf[((size_t)(b * N_ + n0 + nn)) * 64 + cc] = lds[cc * 65 + nn]; // coalesced over c
    }
  }
  if (tid < 64) {
    float s = 0.f;
#pragma unroll
    for (int c = 0; c < 64; ++c) { float v = lds[c * 65 + tid]; s += v * v; }
    sq[b * N_ + n0 + tid] = s;
  }
}

// ---------------- K2a: pure distance GEMM -> orderable u32 keys ----------------
// One 64x128 tile of the per-batch distance matrix per block. No selection
// state -> peak live regs ~85 (acc 32 + av 16 + bv 16 + addr) -> no spills
// (r5/r6: fused kv[16]+cbuf pushed past the RA's 128 cap -> 6 GB scratch).
__global__ __launch_bounds__(256)
void k_dist(const float* __restrict__ xf,
            const float* __restrict__ sq,
            u32* __restrict__ D,
            int panel_r0) {
  __shared__ __align__(16) float sA[TM_ * 64];   // 16 KB, K-blocks xor-swizzled
  __shared__ __align__(16) float sB[TN_ * 64];   // 32 KB, K-blocks xor-swizzled
  __shared__ float sD[TM_ * 65];                 // 16.6 KB half-tile of dots

  const int tid   = threadIdx.x;
  const int mtile = blockIdx.x & 31;             // 32 m-tiles of 128
  const int rtile = blockIdx.x >> 5;
  const int ng0   = panel_r0 + rtile * TM_;      // global row of tile start
  const int b     = ng0 >> 12;
  const int n0    = ng0 & (N_ - 1);
  const int m0    = mtile * TN_;
  const float* __restrict__ xfb = xf + (size_t)b * N_ * 64;
  const float* __restrict__ sqb = sq + b * N_;

  // stage A and B tiles (swizzled): [r][kb*4..+3] at [r*64 + ((kb^(r&15))<<2)]
  {
    const int kb = tid & 15, rr = tid >> 4;      // r = rr+16i -> r&15 == rr
#pragma unroll
    for (int i = 0; i < 4; ++i) {
      int r = rr + 16 * i;
      float4 v = *(const float4*)(xfb + (size_t)(n0 + r) * 64 + kb * 4);
      *(float4*)(sA + r * 64 + ((kb ^ rr) << 2)) = v;
    }
#pragma unroll
    for (int i = 0; i < 8; ++i) {
      int r = rr + 16 * i;
      float4 v = *(const float4*)(xfb + (size_t)(m0 + r) * 64 + kb * 4);
      *(float4*)(sB + r * 64 + ((kb ^ rr) << 2)) = v;
    }
  }
  __syncthreads();

  const int tx = tid & 15;       // col group: owns cols tx+16j
  const int TY = tid >> 4;       // row group: owns rows TY+16i
  float acc[4][8];
#pragma unroll
  for (int i = 0; i < 4; ++i)
#pragma unroll
    for (int j = 0; j < 8; ++j) acc[i][j] = 0.f;
#pragma unroll
  for (int kb = 0; kb < 16; ++kb) {
    float4 av[4];
#pragma unroll
    for (int i = 0; i < 4; ++i)
      av[i] = *(const float4*)(sA + (TY + 16 * i) * 64 + ((kb ^ TY) << 2));
#pragma unroll
    for (int g = 0; g < 2; ++g) {
      float4 bv[4];
#pragma unroll
      for (int j = 0; j < 4; ++j)
        bv[j] = *(const float4*)(sB + (tx + 16 * (g * 4 + j)) * 64 + ((kb ^ tx) << 2));
#pragma unroll
      for (int i = 0; i < 4; ++i)
#pragma unroll
        for (int j = 0; j < 4; ++j)
          acc[i][g * 4 + j] += av[i].x * bv[j].x + av[i].y * bv[j].y
                             + av[i].z * bv[j].z + av[i].w * bv[j].w;
    }
  }

  // epilogue: two 64-col halves through sD, then coalesced key stores
  const int col = tid & 63;
  const int rg4 = tid >> 6;                      // wave id -> uniform row group
#pragma unroll
  for (int half = 0; half < 2; ++half) {
    if (half) __syncthreads();                   // prev half's readers done
#pragma unroll
    for (int i = 0; i < 4; ++i)
#pragma unroll
      for (int j = 0; j < 4; ++j)
        sD[(TY + 16 * i) * 65 + tx + 16 * j] = acc[i][half * 4 + j];
    __syncthreads();
#pragma unroll
    for (int i = 0; i < 16; ++i) {
      int row = rg4 * 16 + i;                    // wave-uniform
      float dot = sD[row * 65 + col];
      int m = m0 + half * 64 + col;
      float d = sqb[n0 + row] + sqb[m] - 2.f * dot;
      u32 u = __float_as_uint(d);
      u ^= (u & 0x80000000u) ? 0xFFFFFFFFu : 0x80000000u;
      D[(size_t)(rtile * TM_ + row) * N_ + m] = u;   // 256 B/wave coalesced
    }
  }
}

// ---------------- K2b: streaming top-16 select over key matrix ----------------
// Thread-per-row, 4 m-splits. Chunks of 32 m staged via LDS in [m][row]
// layout (stride 261 -> 2-way banks). Selection = r2-proven thresh filter +
// batch-drain (cbuf stride 17). No GEMM pressure -> kv[16] in regs is safe.
__global__ __launch_bounds__(256)
void k_select(const u32* __restrict__ D,
              u32* __restrict__ kd,
              u16* __restrict__ ki,
              int panel_r0) {
  __shared__ u32 stage[32 * SEL_STR];            // 33.4 KB
  __shared__ u64 cbuf[256 * BUFSTRIDE_];         // 34.8 KB
  const int tid   = threadIdx.x;
  const int split = blockIdx.x & (SPLIT_ - 1);
  const int r0    = (blockIdx.x >> 2) * 256;     // panel-local row base
  const int mbase = split * (N_ / SPLIT_);       // 1024-col span

  u64 kv[16];
#pragma unroll
  for (int j = 0; j < 16; ++j) kv[j] = ~0ULL;
  u64 thresh = ~0ULL;
  int cnt = 0;
  u64* mybuf = cbuf + tid * BUFSTRIDE_;

  const int mq = tid & 7, rr = tid >> 3;         // staging roles
  for (int ch = 0; ch < 32; ++ch) {
    const int c0 = mbase + ch * 32;
    __syncthreads();                             // prev chunk consumed
#pragma unroll
    for (int p = 0; p < 8; ++p) {
      int row = rr + 32 * p;
      uint4 v = *(const uint4*)(D + (size_t)(r0 + row) * N_ + c0 + mq * 4);
      stage[(mq * 4 + 0) * SEL_STR + row] = v.x;
      stage[(mq * 4 + 1) * SEL_STR + row] = v.y;
      stage[(mq * 4 + 2) * SEL_STR + row] = v.z;
      stage[(mq * 4 + 3) * SEL_STR + row] = v.w;
    }
    __syncthreads();
    for (int i = 0; i < 32; ++i) {
      u32 k32 = stage[i * SEL_STR + tid];        // bank (5i+tid)%32: 2-way, free
      u64 key = ((u64)k32 << 32) | (u32)(c0 + i);
      if (key < thresh) { mybuf[cnt] = key; cnt++; }
      if (__any(cnt == 16)) {                    // batch-drain
        for (int q = 0; q < cnt; ++q) insert16(kv, mybuf[q]);
        cnt = 0;
        thresh = kv[15];
      }
    }
  }
  for (int q = 0; q < cnt; ++q) insert16(kv, mybuf[q]);

  const int rg = panel_r0 + r0 + tid;            // global row
  u32* dp = kd + ((size_t)rg * SPLIT_ + split) * 16;
  u16* ip = ki + ((size_t)rg * SPLIT_ + split) * 16;
#pragma unroll
  for (int j = 0; j < 16; ++j) {
    dp[j] = (u32)(kv[j] >> 32);
    ip[j] = (u16)(kv[j] & 0xFFFFu);
  }
}

// ---------------- K3: merge 4 partial top-16 -> final 16 indices ----------------
__global__ __launch_bounds__(256) void k_merge(const u32* __restrict__ kd,
                                               const u16* __restrict__ ki,
                                               int* __restrict__ knn) {
  int r = blockIdx.x * 256 + threadIdx.x;
  u64 kv[16];
#pragma unroll
  for (int j = 0; j < 16; ++j) kv[j] = ~0ULL;
  const u32* dp = kd + (size_t)r * (SPLIT_ * 16);
  const u16* ip = ki + (size_t)r * (SPLIT_ * 16);
  for (int i = 0; i < SPLIT_ * 16; ++i) {
    u64 key = ((u64)dp[i] << 32) | ip[i];
    insert16(kv, key);
  }
#pragma unroll
  for (int j = 0; j < 16; ++j) knn[r * 16 + j] = (int)(kv[j] & 0xFFFFu);
}

// ---------------- K4: GIN aggregation: h = (1+eps)*xf + sum_k xf[idx] ----------------
__global__ __launch_bounds__(256) void k_aggr(const float* __restrict__ xf,
                                              const int* __restrict__ knn,
                                              const float* __restrict__ eps_gin,
                                              float* __restrict__ h) {
  const int tid = threadIdx.x;
  const int r = blockIdx.x * 4 + (tid >> 6);   // wave per row
  const int c = tid & 63;
  const int b = r >> 12;
  const float* xfb = xf + (size_t)b * N_ * 64;
  const float eps = eps_gin[0];
  float v = (1.f + eps) * xf[(size_t)r * 64 + c];
  const int* kn = knn + r * 16;
#pragma unroll
  for (int j = 0; j < 16; ++j) {
    int m = kn[j];                              // wave-uniform scalar load
    v += xfb[(size_t)m * 64 + c];               // coalesced 256B row read
  }
  h[(size_t)r * 64 + c] = v;
}

// ---------------- K5: h1 = h @ w1 + b1, plus BN partial sums ----------------
__global__ __launch_bounds__(256) void k_gemm1(const float* __restrict__ h,
                                               const float* __restrict__ w1,
                                               const float* __restrict__ b1,
                                               float* __restrict__ h1,
                                               float* __restrict__ bn_acc) {
  __shared__ float w[64 * 64];
  __shared__ float rs[4][64], rs2[4][64];
  const int tid = threadIdx.x;
#pragma unroll
  for (int i = 0; i < 16; ++i) w[tid + i * 256] = w1[tid + i * 256];
  __syncthreads();
  const int o = tid & 63;
  const int q = tid >> 6;
  const int r0 = blockIdx.x * 64;
  const float bias = b1[o];
  float s = 0.f, s2 = 0.f;
#pragma unroll
  for (int i = 0; i < 16; ++i) {
    int row = r0 + q + i * 4;                   // wave-uniform row
    const float* hr = h + (size_t)row * 64;
    float acc = bias;
#pragma unroll
    for (int c = 0; c < 64; ++c) acc += hr[c] * w[c * 64 + o];
    h1[(size_t)row * 64 + o] = acc;
    s += acc; s2 += acc * acc;
  }
  rs[q][o] = s; rs2[q][o] = s2;
  __syncthreads();
  if (tid < 64) {
    float ts  = rs[0][tid] + rs[1][tid] + rs[2][tid] + rs[3][tid];
    float ts2 = rs2[0][tid] + rs2[1][tid] + rs2[2][tid] + rs2[3][tid];
    atomicAdd(&bn_acc[tid], ts);
    atomicAdd(&bn_acc[64 + tid], ts2);
  }
}

// ---------------- K6: finalize BN -> per-channel scale/shift ----------------
__global__ void k_bnfin(const float* __restrict__ bn_acc,
                        const float* __restrict__ gamma,
                        const float* __restrict__ beta,
                        float* __restrict__ bn_par) {
  int o = threadIdx.x;   // 64 threads
  const float inv = 1.f / (float)ROWS_;
  float mean = bn_acc[o] * inv;
  float var  = bn_acc[64 + o] * inv - mean * mean;
  float sc = gamma[o] * rsqrtf(var + 1e-5f);
  bn_par[o] = sc;
  bn_par[64 + o] = beta[o] - mean * sc;
}

// ---------------- K7: BN apply + GELU(erf) + GEMM2 + transposed store ----------------
__global__ __launch_bounds__(256) void k_final(const float* __restrict__ h1,
                                               const float* __restrict__ bn_par,
                                               const float* __restrict__ w2,
                                               const float* __restrict__ b2,
                                               float* __restrict__ out) {
  __shared__ float w[64 * 64];
  __shared__ float hg[64 * 65];                 // padded: kills stride-64 conflicts
  const int tid = threadIdx.x;
#pragma unroll
  for (int i = 0; i < 16; ++i) w[tid + i * 256] = w2[tid + i * 256];
  const int r0 = blockIdx.x * 64;
  const int b  = r0 >> 12;
  const int n0 = r0 & (N_ - 1);
  const int o = tid & 63;
  const int q = tid >> 6;
  const float sc = bn_par[o], sh = bn_par[64 + o];
#pragma unroll
  for (int i = 0; i < 16; ++i) {
    int rl = q + i * 4;
    float v = h1[(size_t)(r0 + rl) * 64 + o] * sc + sh;
    float g = 0.5f * v * (1.f + erff(v * 0.70710678118654752f));
    hg[rl * 65 + o] = g;
  }
  __syncthreads();
  const int nl = tid & 63;
#pragma unroll
  for (int i = 0; i < 16; ++i) {
    int o2 = q + i * 4;                         // wave-uniform
    float acc = b2[o2];
#pragma unroll
    for (int oo = 0; oo < 64; ++oo) acc += hg[nl * 65 + oo] * w[oo * 64 + o2];
    out[((size_t)(b * 64 + o2)) * N_ + n0 + nl] = acc;  // coalesced over n
  }
}

extern "C" void kernel_launch(void* const* d_in, const int* in_sizes, int n_in,
                              void* d_out, int out_size, void* d_ws, size_t ws_size,
                              hipStream_t stream) {
  const float* x     = (const float*)d_in[0];
  const float* w1    = (const float*)d_in[1];
  const float* b1    = (const float*)d_in[2];
  const float* gamma = (const float*)d_in[3];
  const float* beta  = (const float*)d_in[4];
  const float* w2    = (const float*)d_in[5];
  const float* b2    = (const float*)d_in[6];
  const float* eps_g = (const float*)d_in[7];
  float* out = (float*)d_out;

  char* ws = (char*)d_ws;
  float* xf   = (float*)(ws + OFF_XF);
  float* sq   = (float*)(ws + OFF_SQ);
  u32*   kd   = (u32*)  (ws + OFF_KD);
  u16*   ki   = (u16*)  (ws + OFF_KI);
  int*   knn  = (int*)  (ws + OFF_IDX);
  float* h    = (float*)(ws + OFF_H);     // aliases kd (dead after merge)
  float* h1   = (float*)(ws + OFF_H1);    // aliases ki+knn (dead after aggr)
  float* bn_acc = (float*)(ws + OFF_BN);
  float* bn_par = (float*)(ws + OFF_BN + 512);
  u32*   Dp   = (u32*)  (ws + OFF_D);

  // panel count: smallest P whose D-panel (536 MB / P) fits the workspace.
  // (ws_size is constant across calls -> identical launch sequence, graph-safe)
  size_t availD = ws_size > (size_t)OFF_D ? ws_size - (size_t)OFF_D : 0;
  int P = 64;                                    // 8.4 MB fallback (fits r1's 36 MB floor)
  if      (availD >= 536870912ull) P = 1;
  else if (availD >= 268435456ull) P = 2;
  else if (availD >= 134217728ull) P = 4;
  else if (availD >=  67108864ull) P = 8;
  else if (availD >=  33554432ull) P = 16;
  else if (availD >=  16777216ull) P = 32;
  const int rows_panel = ROWS_ / P;

  k_transpose<<<512, 256, 0, stream>>>(x, xf, sq, bn_acc);
  for (int p = 0; p < P; ++p) {
    const int pr0 = p * rows_panel;
    k_dist<<<(rows_panel / TM_) * 32, 256, 0, stream>>>(xf, sq, Dp, pr0);
    k_select<<<(rows_panel / 256) * SPLIT_, 256, 0, stream>>>(Dp, kd, ki, pr0);
  }
  k_merge<<<ROWS_ / 256, 256, 0, stream>>>(kd, ki, knn);
  k_aggr<<<ROWS_ / 4, 256, 0, stream>>>(xf, knn, eps_g, h);
  k_gemm1<<<ROWS_ / 64, 256, 0, stream>>>(h, w1, b1, h1, bn_acc);
  k_bnfin<<<1, 64, 0, stream>>>(bn_acc, gamma, beta, bn_par);
  k_final<<<ROWS_ / 64, 256, 0, stream>>>(h1, bn_par, w2, b2, out);
}